// Round 3
// baseline (4117.318 us; speedup 1.0000x reference)
//
#include <hip/hip_runtime.h>
#include <hip/hip_bf16.h>
#include <cstddef>

// Network: op(x) [5 edge branches, reflect-101, per-sample norm] -> conv1(160->32)
// -> [pool conv]x3 -> [deconv conv]x3 -> out = x * y.  All fp32.
// B=4, C=32, H=W=512.
//
// This version never materializes the 160-channel operator tensor:
//  - k_opstats recomputes the 5 stencils from x and produces per-(b,branch)
//    partial sums -> k_stats -> (mean, 1/std).
//  - k_conv1f recomputes the stencils inside its tile loop (normalization
//    folded) and applies conv1 directly. Reflect-101 is applied per tap.

constexpr int Bn = 4, Cn = 32, Hn = 512, Wn = 512;
constexpr int PLANE = Hn * Wn;  // 262144

static __device__ __forceinline__ int reflect_idx(int i, int n) {
  return i < 0 ? -i : (i >= n ? 2 * n - 2 - i : i);
}

// Combined stencils (0.5*(Kx+Ky) folded):
//  b1 sobel:   [[-1,-1,0],[-1,0,1],[0,1,1]]
//  b2 scharr:  [[-3,-5,0],[-5,0,5],[0,5,3]]
//  b3 laplace: [[2,0,2],[0,-8,0],[2,0,2]]
//  b4 roberts: [[-.5,-.5,0],[.5,.5,0],[0,0,0]] (taps n00,n01,n10,n11)
//  b5 prewitt: [[0,.5,1],[-.5,0,.5],[-1,-.5,0]]
#define BRANCH_VALS(n00, n01, n02, n10, n11, n12, n20, n21, n22, v1, v2, v3, v4, v5)        \
  do {                                                                                      \
    v1 = -(n00 + n01 + n10) + (n12 + n21 + n22);                                            \
    v2 = -3.f * n00 - 5.f * n01 - 5.f * n10 + 5.f * n12 + 5.f * n21 + 3.f * n22;            \
    v3 = 2.f * (n00 + n02 + n20 + n22) - 8.f * n11;                                         \
    v4 = 0.5f * (-n00 - n01 + n10 + n11);                                                   \
    v5 = 0.5f * n01 + n02 - 0.5f * n10 + 0.5f * n12 - n20 - 0.5f * n21;                     \
  } while (0)

// ---------------------------------------------------------------------------
// K1: per-(b,branch) partial sums (sum, sumsq) of raw branch maps, stencils
// recomputed from x. Block = (b, c, 8-row chunk), 128 threads x 4 cols.
// Rolling 3-row window -> ~1.25x read amplification.
// ---------------------------------------------------------------------------
__global__ void __launch_bounds__(128) k_opstats(const float* __restrict__ x,
                                                 float* __restrict__ partS,
                                                 float* __restrict__ partQ) {
  int bid = blockIdx.x;          // 4*32*64 = 8192 blocks
  int b = bid >> 11;
  int local = bid & 2047;
  int c = local >> 6;
  int chunk = local & 63;
  int t = threadIdx.x;
  int w0 = t * 4;
  const float* xp = x + (size_t)(b * Cn + c) * PLANE;
  int h0 = chunk * 8;

  int ci[6];
#pragma unroll
  for (int j = 0; j < 6; j++) ci[j] = reflect_idx(w0 - 1 + j, Wn);

  float ap[6], ac[6], an[6];
  {
    const float* rp = xp + reflect_idx(h0 - 1, Hn) * Wn;
#pragma unroll
    for (int j = 0; j < 6; j++) ap[j] = rp[ci[j]];
  }
  {
    const float* rp = xp + h0 * Wn;
#pragma unroll
    for (int j = 0; j < 6; j++) ac[j] = rp[ci[j]];
  }

  float s[5] = {0, 0, 0, 0, 0}, q[5] = {0, 0, 0, 0, 0};
#pragma unroll
  for (int r = 0; r < 8; ++r) {
    int h = h0 + r;
    const float* rp = xp + reflect_idx(h + 1, Hn) * Wn;
#pragma unroll
    for (int j = 0; j < 6; j++) an[j] = rp[ci[j]];
#pragma unroll
    for (int k = 0; k < 4; ++k) {
      float v1, v2, v3, v4, v5;
      BRANCH_VALS(ap[k], ap[k + 1], ap[k + 2], ac[k], ac[k + 1], ac[k + 2],
                  an[k], an[k + 1], an[k + 2], v1, v2, v3, v4, v5);
      s[0] += v1; q[0] += v1 * v1;
      s[1] += v2; q[1] += v2 * v2;
      s[2] += v3; q[2] += v3 * v3;
      s[3] += v4; q[3] += v4 * v4;
      s[4] += v5; q[4] += v5 * v5;
    }
#pragma unroll
    for (int j = 0; j < 6; j++) { ap[j] = ac[j]; ac[j] = an[j]; }
  }

#pragma unroll
  for (int i = 0; i < 5; i++) {
    float ss = s[i], qq = q[i];
#pragma unroll
    for (int off = 32; off > 0; off >>= 1) {
      ss += __shfl_down(ss, off);
      qq += __shfl_down(qq, off);
    }
    if ((t & 63) == 0) {
      int wv = t >> 6;
      int g = b * 5 + i;
      int idx = (c * 64 + chunk) * 2 + wv;  // 0..4095
      partS[(size_t)g * 4096 + idx] = ss;
      partQ[(size_t)g * 4096 + idx] = qq;
    }
  }
}

// ---------------------------------------------------------------------------
// K2: reduce partials -> (mean, 1/std) per (b, branch). 20 blocks.
// ---------------------------------------------------------------------------
__global__ void __launch_bounds__(256) k_stats(const float* __restrict__ partS,
                                               const float* __restrict__ partQ,
                                               float* __restrict__ stats) {
  __shared__ float red[256];
  int g = blockIdx.x;
  int t = threadIdx.x;
  float ss = 0.f, qq = 0.f;
  const float* ps = partS + (size_t)g * 4096;
  const float* pq = partQ + (size_t)g * 4096;
  for (int i = t; i < 4096; i += 256) {
    ss += ps[i];
    qq += pq[i];
  }
  red[t] = ss;
  __syncthreads();
  for (int o = 128; o > 0; o >>= 1) {
    if (t < o) red[t] += red[t + o];
    __syncthreads();
  }
  float S = red[0];
  __syncthreads();
  red[t] = qq;
  __syncthreads();
  for (int o = 128; o > 0; o >>= 1) {
    if (t < o) red[t] += red[t + o];
    __syncthreads();
  }
  if (t == 0) {
    const float N = 8388608.0f;  // 32*512*512
    float mean = S / N;
    float var = red[0] / N - mean * mean;
    stats[g * 2] = mean;
    stats[g * 2 + 1] = 1.0f / sqrtf(var);
  }
}

// ---------------------------------------------------------------------------
// K3: fused operator + conv1 (160->32, 3x3, zero pad on branch maps).
// Block = 16x16 pixels. Per input channel c: stage 20x20 reflect tile of x,
// compute 5 normalized branch tiles (18x18), then 5*32*9 FMA per thread.
// ---------------------------------------------------------------------------
__global__ void __launch_bounds__(256) k_conv1f(const float* __restrict__ x,
                                                const float* __restrict__ stats,
                                                const float* __restrict__ wgt,
                                                const float* __restrict__ bias,
                                                float* __restrict__ out) {
  __shared__ float xs[20][21];
  __shared__ float bt[5][18][19];
  int tx = threadIdx.x, ty = threadIdx.y;
  int b = blockIdx.z;
  int h0 = blockIdx.y * 16, w0 = blockIdx.x * 16;
  int t = ty * 16 + tx;

  float mean[5], istd[5];
#pragma unroll
  for (int br = 0; br < 5; br++) {
    mean[br] = stats[(b * 5 + br) * 2];
    istd[br] = stats[(b * 5 + br) * 2 + 1];
  }

  float acc[32];
#pragma unroll
  for (int i = 0; i < 32; i++) acc[i] = 0.f;

  for (int c = 0; c < 32; ++c) {
    const float* xp = x + (size_t)(b * Cn + c) * PLANE;
    for (int s = t; s < 400; s += 256) {
      int r = s / 20, cc = s - r * 20;
      int gh = reflect_idx(h0 - 2 + r, Hn);
      int gw = reflect_idx(w0 - 2 + cc, Wn);
      xs[r][cc] = xp[gh * Wn + gw];
    }
    __syncthreads();
    for (int s = t; s < 324; s += 256) {
      int r = s / 18, cc = s - r * 18;
      int gh = h0 - 1 + r, gw = w0 - 1 + cc;
      bool inside = (gh >= 0 && gh < Hn && gw >= 0 && gw < Wn);
      float n00 = xs[r][cc],     n01 = xs[r][cc + 1],     n02 = xs[r][cc + 2];
      float n10 = xs[r + 1][cc], n11 = xs[r + 1][cc + 1], n12 = xs[r + 1][cc + 2];
      float n20 = xs[r + 2][cc], n21 = xs[r + 2][cc + 1], n22 = xs[r + 2][cc + 2];
      float v1, v2, v3, v4, v5;
      BRANCH_VALS(n00, n01, n02, n10, n11, n12, n20, n21, n22, v1, v2, v3, v4, v5);
      bt[0][r][cc] = inside ? (v1 - mean[0]) * istd[0] : 0.f;
      bt[1][r][cc] = inside ? (v2 - mean[1]) * istd[1] : 0.f;
      bt[2][r][cc] = inside ? (v3 - mean[2]) * istd[2] : 0.f;
      bt[3][r][cc] = inside ? (v4 - mean[3]) * istd[3] : 0.f;
      bt[4][r][cc] = inside ? (v5 - mean[4]) * istd[4] : 0.f;
    }
    __syncthreads();
#pragma unroll
    for (int br = 0; br < 5; ++br) {
      float n00 = bt[br][ty][tx],     n01 = bt[br][ty][tx + 1],     n02 = bt[br][ty][tx + 2];
      float n10 = bt[br][ty + 1][tx], n11 = bt[br][ty + 1][tx + 1], n12 = bt[br][ty + 1][tx + 2];
      float n20 = bt[br][ty + 2][tx], n21 = bt[br][ty + 2][tx + 1], n22 = bt[br][ty + 2][tx + 2];
      const float* wp = wgt + (br * 32 + c) * 9;  // + oc*1440, wave-uniform
#pragma unroll
      for (int oc = 0; oc < 32; ++oc) {
        const float* w9 = wp + oc * 1440;
        float a0 = acc[oc];
        a0 = fmaf(w9[0], n00, a0); a0 = fmaf(w9[1], n01, a0); a0 = fmaf(w9[2], n02, a0);
        a0 = fmaf(w9[3], n10, a0); a0 = fmaf(w9[4], n11, a0); a0 = fmaf(w9[5], n12, a0);
        a0 = fmaf(w9[6], n20, a0); a0 = fmaf(w9[7], n21, a0); a0 = fmaf(w9[8], n22, a0);
        acc[oc] = a0;
      }
    }
    __syncthreads();
  }
  int h = h0 + ty, w = w0 + tx;
  size_t ob = ((size_t)(b * 32) * Hn + h) * Wn + w;
#pragma unroll
  for (int oc = 0; oc < 32; oc++) out[ob + (size_t)oc * PLANE] = acc[oc] + bias[oc];
}

// ---------------------------------------------------------------------------
// Generic conv 32->32, 3x3, zero pad; optional fused final multiply by xorig.
// ---------------------------------------------------------------------------
template <bool FUSE>
__global__ void __launch_bounds__(256) k_conv32(const float* __restrict__ in,
                                                const float* __restrict__ wgt,
                                                const float* __restrict__ bias,
                                                float* __restrict__ out,
                                                const float* __restrict__ xorig,
                                                int H, int W) {
  __shared__ float tile[18][19];
  int tx = threadIdx.x, ty = threadIdx.y;
  int b = blockIdx.z;
  int h0 = blockIdx.y * 16, w0 = blockIdx.x * 16;
  int h = h0 + ty, w = w0 + tx;
  int t = ty * 16 + tx;
  int plane = H * W;

  float acc[32];
#pragma unroll
  for (int i = 0; i < 32; i++) acc[i] = 0.f;

  for (int ic = 0; ic < 32; ++ic) {
    const float* ip = in + (size_t)(b * 32 + ic) * plane;
    for (int s = t; s < 324; s += 256) {
      int r = s / 18, cc = s - r * 18;
      int gh = h0 + r - 1, gw = w0 + cc - 1;
      float v = 0.f;
      if (gh >= 0 && gh < H && gw >= 0 && gw < W) v = ip[gh * W + gw];
      tile[r][cc] = v;
    }
    __syncthreads();
    float n00 = tile[ty][tx],     n01 = tile[ty][tx + 1],     n02 = tile[ty][tx + 2];
    float n10 = tile[ty + 1][tx], n11 = tile[ty + 1][tx + 1], n12 = tile[ty + 1][tx + 2];
    float n20 = tile[ty + 2][tx], n21 = tile[ty + 2][tx + 1], n22 = tile[ty + 2][tx + 2];
    const float* wp = wgt + ic * 9;
#pragma unroll
    for (int oc = 0; oc < 32; ++oc) {
      const float* w9 = wp + oc * 288;  // uniform -> scalar loads
      float a0 = acc[oc];
      a0 = fmaf(w9[0], n00, a0); a0 = fmaf(w9[1], n01, a0); a0 = fmaf(w9[2], n02, a0);
      a0 = fmaf(w9[3], n10, a0); a0 = fmaf(w9[4], n11, a0); a0 = fmaf(w9[5], n12, a0);
      a0 = fmaf(w9[6], n20, a0); a0 = fmaf(w9[7], n21, a0); a0 = fmaf(w9[8], n22, a0);
      acc[oc] = a0;
    }
    __syncthreads();
  }
  size_t ob = ((size_t)(b * 32) * H + h) * W + w;
#pragma unroll
  for (int oc = 0; oc < 32; oc++) {
    float v = acc[oc] + bias[oc];
    size_t idx = ob + (size_t)oc * plane;
    if (FUSE) v *= xorig[idx];
    out[idx] = v;
  }
}

// ---------------------------------------------------------------------------
// maxpool 2x2 stride 2
// ---------------------------------------------------------------------------
__global__ void __launch_bounds__(256) k_maxpool(const float* __restrict__ in,
                                                 float* __restrict__ out,
                                                 int Ho, int Wo, int total) {
  int idx = blockIdx.x * 256 + threadIdx.x;
  if (idx >= total) return;
  int w = idx % Wo;
  int rest = idx / Wo;
  int h = rest % Ho;
  int ch = rest / Ho;
  int Wi = Wo * 2;
  const float* p = in + ((size_t)ch * (Ho * 2) + 2 * h) * Wi + 2 * w;
  out[idx] = fmaxf(fmaxf(p[0], p[1]), fmaxf(p[Wi], p[Wi + 1]));
}

// ---------------------------------------------------------------------------
// deconv 2x2 stride 2: out[b,oc,2h+p,2w+q] = sum_ic in[b,ic,h,w]*w[ic,oc,p,q]+b
// ---------------------------------------------------------------------------
__global__ void __launch_bounds__(256) k_deconv(const float* __restrict__ in,
                                                const float* __restrict__ wgt,
                                                const float* __restrict__ bias,
                                                float* __restrict__ out,
                                                int Hi, int Wi) {
  int tx = threadIdx.x, ty = threadIdx.y;
  int z = blockIdx.z;
  int b = z >> 5, oc = z & 31;
  int Ho = Hi * 2, Wo = Wi * 2;
  int w = blockIdx.x * 16 + tx, h = blockIdx.y * 16 + ty;
  int hi = h >> 1, wi = w >> 1, p = h & 1, qq = w & 1;
  const float* ip = in + (size_t)(b * 32) * Hi * Wi;
  float acc = 0.f;
#pragma unroll
  for (int ic = 0; ic < 32; ++ic) {
    float v = ip[((size_t)ic * Hi + hi) * Wi + wi];
    float4 w4 = *(const float4*)&wgt[(ic * 32 + oc) * 4];
    float sel = p ? (qq ? w4.w : w4.z) : (qq ? w4.y : w4.x);
    acc = fmaf(v, sel, acc);
  }
  out[((size_t)(b * 32 + oc) * Ho + h) * Wo + w] = acc + bias[oc];
}

// ---------------------------------------------------------------------------
extern "C" void kernel_launch(void* const* d_in, const int* in_sizes, int n_in,
                              void* d_out, int out_size, void* d_ws, size_t ws_size,
                              hipStream_t stream) {
  const float* x   = (const float*)d_in[0];
  const float* w1  = (const float*)d_in[1];
  const float* b1  = (const float*)d_in[2];
  const float* w2  = (const float*)d_in[3];
  const float* b2  = (const float*)d_in[4];
  const float* w3  = (const float*)d_in[5];
  const float* b3  = (const float*)d_in[6];
  const float* w4  = (const float*)d_in[7];
  const float* b4  = (const float*)d_in[8];
  const float* w5  = (const float*)d_in[9];
  const float* b5  = (const float*)d_in[10];
  const float* w6  = (const float*)d_in[11];
  const float* b6  = (const float*)d_in[12];
  const float* w7  = (const float*)d_in[13];
  const float* b7  = (const float*)d_in[14];
  const float* dw1 = (const float*)d_in[15];
  const float* db1 = (const float*)d_in[16];
  const float* dw2 = (const float*)d_in[17];
  const float* db2 = (const float*)d_in[18];
  const float* dw3 = (const float*)d_in[19];
  const float* db3 = (const float*)d_in[20];
  float* out = (float*)d_out;
  float* ws = (float*)d_ws;

  // workspace layout (floats); total ~76.7M floats ~= 307 MB
  float* t1    = ws;                  // 33,554,432 (dead after pool1)
  float* dc3   = ws;                  // reuses t1's region
  float* p1    = ws + 33554432ull;    // 8,388,608
  float* t2    = ws + 41943040ull;    // 8,388,608
  float* p2    = ws + 50331648ull;    // 2,097,152
  float* t3    = ws + 52428800ull;    // 2,097,152
  float* p3    = ws + 54525952ull;    //   524,288
  float* t4    = ws + 55050240ull;    //   524,288
  float* dc1   = ws + 55574528ull;    // 2,097,152
  float* t5    = ws + 57671680ull;    // 2,097,152
  float* dc2   = ws + 59768832ull;    // 8,388,608
  float* t6    = ws + 68157440ull;    // 8,388,608
  float* partS = ws + 76546048ull;    //    81,920
  float* partQ = ws + 76627968ull;    //    81,920
  float* stats = ws + 76709888ull;    //        40

  dim3 blk2(16, 16);

  // 1) operator stats (stencils recomputed from x)
  k_opstats<<<8192, 128, 0, stream>>>(x, partS, partQ);
  k_stats<<<20, 256, 0, stream>>>(partS, partQ, stats);
  // 2) fused operator + conv1 (norm folded)
  k_conv1f<<<dim3(32, 32, 4), blk2, 0, stream>>>(x, stats, w1, b1, t1);
  // 3) pool -> 256, conv2
  k_maxpool<<<(4 * 32 * 256 * 256) / 256, 256, 0, stream>>>(t1, p1, 256, 256, 4 * 32 * 256 * 256);
  k_conv32<false><<<dim3(16, 16, 4), blk2, 0, stream>>>(p1, w2, b2, t2, nullptr, 256, 256);
  // 4) pool -> 128, conv3
  k_maxpool<<<(4 * 32 * 128 * 128) / 256, 256, 0, stream>>>(t2, p2, 128, 128, 4 * 32 * 128 * 128);
  k_conv32<false><<<dim3(8, 8, 4), blk2, 0, stream>>>(p2, w3, b3, t3, nullptr, 128, 128);
  // 5) pool -> 64, conv4
  k_maxpool<<<(4 * 32 * 64 * 64) / 256, 256, 0, stream>>>(t3, p3, 64, 64, 4 * 32 * 64 * 64);
  k_conv32<false><<<dim3(4, 4, 4), blk2, 0, stream>>>(p3, w4, b4, t4, nullptr, 64, 64);
  // 6) deconv1 64->128, conv5
  k_deconv<<<dim3(8, 8, 128), blk2, 0, stream>>>(t4, dw1, db1, dc1, 64, 64);
  k_conv32<false><<<dim3(8, 8, 4), blk2, 0, stream>>>(dc1, w5, b5, t5, nullptr, 128, 128);
  // 7) deconv2 128->256, conv6
  k_deconv<<<dim3(16, 16, 128), blk2, 0, stream>>>(t5, dw2, db2, dc2, 128, 128);
  k_conv32<false><<<dim3(16, 16, 4), blk2, 0, stream>>>(dc2, w6, b6, t6, nullptr, 256, 256);
  // 8) deconv3 256->512, conv7 + fused orig*y
  k_deconv<<<dim3(32, 32, 128), blk2, 0, stream>>>(t6, dw3, db3, dc3, 256, 256);
  k_conv32<true><<<dim3(32, 32, 4), blk2, 0, stream>>>(dc3, w7, b7, out, x, 512, 512);
}

// Round 4
// 966.873 us; speedup vs baseline: 4.2584x; 4.2584x over previous
//
#include <hip/hip_runtime.h>
#include <hip/hip_bf16.h>
#include <cstddef>

// B=4, C=32, H=W=512. Pipeline:
//  k_prep_shared: conv2..7 + deconv weights -> bf16 MFMA A-layout
//  per b: k_opfused (stencils -> bf16 NHWC raw maps + stats partials)
//         k_stats5 -> (mean, istd);  k_prep_b (fold norm into conv1 W/bias)
//         k_conv_mfma<160> (conv1)
//  then pools / convs / deconvs all NHWC bf16 MFMA; conv7 fuses *x, fp32 out.

typedef unsigned short u16;
typedef unsigned int uint;
typedef __attribute__((ext_vector_type(8))) short short8v;
typedef __attribute__((ext_vector_type(4))) float float4v;

__device__ __forceinline__ float b2f(u16 u) {
  union { uint i; float f; } c; c.i = ((uint)u) << 16; return c.f;
}
__device__ __forceinline__ u16 f2b(float f) {
  union { float f; uint i; } c; c.f = f;
  uint r = c.i + 0x7FFFu + ((c.i >> 16) & 1u);
  return (u16)(r >> 16);
}

// Combined stencils (0.5*(Kx+Ky) folded); verified vs reference in round 3.
#define BRANCH_VALS(n00, n01, n02, n10, n11, n12, n20, n21, n22, v1, v2, v3, v4, v5)        \
  do {                                                                                      \
    v1 = -(n00 + n01 + n10) + (n12 + n21 + n22);                                            \
    v2 = -3.f * n00 - 5.f * n01 - 5.f * n10 + 5.f * n12 + 5.f * n21 + 3.f * n22;            \
    v3 = 2.f * (n00 + n02 + n20 + n22) - 8.f * n11;                                         \
    v4 = 0.5f * (-n00 - n01 + n10 + n11);                                                   \
    v5 = 0.5f * n01 + n02 - 0.5f * n10 + 0.5f * n12 - n20 - 0.5f * n21;                     \
  } while (0)

// ---------------------------------------------------------------------------
// K1: fused operator pass for one sample b.
// Grid (8 wchunks, 512 h). Block 256: px = t&63 (w within 64-chunk), cg = t>>6.
// Computes v1..v5 fp32, accumulates per-(br) stats partials, writes raw bf16
// branch maps NHWC [h][w][br*32+c] via LDS transpose ([ch][px], +2 pad line).
// ---------------------------------------------------------------------------
__global__ void __launch_bounds__(256) k_opfused(const float* __restrict__ x, int b,
                                                 u16* __restrict__ opm,
                                                 float* __restrict__ partS,
                                                 float* __restrict__ partQ) {
  __shared__ u16 lin[160 * 66];
  int t = threadIdx.x;
  int px = t & 63, cg = t >> 6;
  int h = blockIdx.y;
  int w = blockIdx.x * 64 + px;
  int hm = h == 0 ? 1 : h - 1, hp = h == 511 ? 510 : h + 1;
  int wm = w == 0 ? 1 : w - 1, wp = w == 511 ? 510 : w + 1;

  float sv[5] = {0, 0, 0, 0, 0}, qv[5] = {0, 0, 0, 0, 0};
#pragma unroll
  for (int it = 0; it < 8; ++it) {
    int c = it * 4 + cg;
    const float* xp = x + ((size_t)(b * 32 + c) * 512) * 512;
    const float* r0 = xp + (size_t)hm * 512;
    const float* r1 = xp + (size_t)h * 512;
    const float* r2 = xp + (size_t)hp * 512;
    float n00 = r0[wm], n01 = r0[w], n02 = r0[wp];
    float n10 = r1[wm], n11 = r1[w], n12 = r1[wp];
    float n20 = r2[wm], n21 = r2[w], n22 = r2[wp];
    float v1, v2, v3, v4, v5;
    BRANCH_VALS(n00, n01, n02, n10, n11, n12, n20, n21, n22, v1, v2, v3, v4, v5);
    sv[0] += v1; qv[0] += v1 * v1;
    sv[1] += v2; qv[1] += v2 * v2;
    sv[2] += v3; qv[2] += v3 * v3;
    sv[3] += v4; qv[3] += v4 * v4;
    sv[4] += v5; qv[4] += v5 * v5;
    lin[(c) * 66 + px] = f2b(v1);
    lin[(32 + c) * 66 + px] = f2b(v2);
    lin[(64 + c) * 66 + px] = f2b(v3);
    lin[(96 + c) * 66 + px] = f2b(v4);
    lin[(128 + c) * 66 + px] = f2b(v5);
  }

#pragma unroll
  for (int br = 0; br < 5; ++br) {
    float ss = sv[br], qq = qv[br];
#pragma unroll
    for (int off = 32; off > 0; off >>= 1) {
      ss += __shfl_down(ss, off);
      qq += __shfl_down(qq, off);
    }
    if ((t & 63) == 0) {
      int widx = (blockIdx.y * 8 + blockIdx.x) * 4 + (t >> 6);
      partS[br * 16384 + widx] = ss;
      partQ[br * 16384 + widx] = qq;
    }
  }
  __syncthreads();

  size_t obase = ((size_t)h * 512 + blockIdx.x * 64) * 160;
#pragma unroll
  for (int i = 0; i < 20; ++i) {
    int u = t + i * 256;             // 5120 units = (pxpair 0..31) x (ch 0..159)
    int ch = u % 160, pxp = u / 160;
    uint v = *(const uint*)&lin[ch * 66 + pxp * 2];
    opm[obase + (size_t)(pxp * 2) * 160 + ch] = (u16)v;
    opm[obase + (size_t)(pxp * 2 + 1) * 160 + ch] = (u16)(v >> 16);
  }
}

// ---------------------------------------------------------------------------
// K2: reduce partials -> stats (mean, 1/std) per branch, one sample. 5 blocks.
// ---------------------------------------------------------------------------
__global__ void __launch_bounds__(256) k_stats5(const float* __restrict__ partS,
                                                const float* __restrict__ partQ,
                                                float* __restrict__ stats) {
  __shared__ float red[256];
  int br = blockIdx.x, t = threadIdx.x;
  float ss = 0.f, qq = 0.f;
  for (int i = t; i < 16384; i += 256) {
    ss += partS[br * 16384 + i];
    qq += partQ[br * 16384 + i];
  }
  red[t] = ss;
  __syncthreads();
  for (int o = 128; o > 0; o >>= 1) {
    if (t < o) red[t] += red[t + o];
    __syncthreads();
  }
  float S = red[0];
  __syncthreads();
  red[t] = qq;
  __syncthreads();
  for (int o = 128; o > 0; o >>= 1) {
    if (t < o) red[t] += red[t + o];
    __syncthreads();
  }
  if (t == 0) {
    const float N = 8388608.0f;
    float mean = S / N;
    float var = red[0] / N - mean * mean;
    stats[br * 2] = mean;
    stats[br * 2 + 1] = 1.0f / sqrtf(var);
  }
}

// ---------------------------------------------------------------------------
// K3a: shared weight prep: conv2..7 -> A[tap][oc][ic] bf16; deconv ->
// Adc[par][oc][ic] bf16 (A[oc][ic] = dw[ic][oc][p][q]).
// ---------------------------------------------------------------------------
__global__ void __launch_bounds__(256) k_prep_shared(
    const float* w2, const float* w3, const float* w4, const float* w5,
    const float* w6, const float* w7, const float* dw1, const float* dw2,
    const float* dw3, u16* A2, u16* A3, u16* A4, u16* A5, u16* A6, u16* A7,
    u16* Ad1, u16* Ad2, u16* Ad3) {
  int id = blockIdx.x * 256 + threadIdx.x;
  if (id < 55296) {
    int s = id / 9216, r = id % 9216;
    int tap = r / 1024, oc = (r >> 5) & 31, ic = r & 31;
    const float* w = s == 0 ? w2 : s == 1 ? w3 : s == 2 ? w4 : s == 3 ? w5 : s == 4 ? w6 : w7;
    u16* A = s == 0 ? A2 : s == 1 ? A3 : s == 2 ? A4 : s == 3 ? A5 : s == 4 ? A6 : A7;
    A[r] = f2b(w[(oc * 32 + ic) * 9 + tap]);
  } else if (id < 67584) {
    int r = id - 55296;
    int s = r / 4096, e = r % 4096;
    int par = e >> 10, oc = (e >> 5) & 31, ic = e & 31;
    const float* w = s == 0 ? dw1 : s == 1 ? dw2 : dw3;
    u16* A = s == 0 ? Ad1 : s == 1 ? Ad2 : Ad3;
    A[e] = f2b(w[(ic * 32 + oc) * 4 + par]);
  }
}

// ---------------------------------------------------------------------------
// K3b: per-sample conv1 prep: A1[br][tap][oc][ic] = bf16(w1 * istd_br);
// bias1[oc] = b1[oc] - sum w1*mean*istd.
// ---------------------------------------------------------------------------
__global__ void __launch_bounds__(256) k_prep_b(const float* __restrict__ w1,
                                                const float* __restrict__ b1,
                                                const float* __restrict__ stats,
                                                u16* __restrict__ A1,
                                                float* __restrict__ bias1) {
  int bx = blockIdx.x, t = threadIdx.x;
  if (bx < 180) {
    int e = bx * 256 + t;  // < 46080
    int br = e / 9216, r = e % 9216;
    int tap = r / 1024, oc = (r >> 5) & 31, ic = e & 31;
    A1[e] = f2b(w1[(oc * 160 + br * 32 + ic) * 9 + tap] * stats[br * 2 + 1]);
  } else if (t < 32) {
    int oc = t;
    float s = 0.f;
    for (int ch = 0; ch < 160; ++ch) {
      int br = ch >> 5;
      float mi = stats[br * 2] * stats[br * 2 + 1];
      const float* wp = w1 + (size_t)(oc * 160 + ch) * 9;
      float ws = 0.f;
#pragma unroll
      for (int tap = 0; tap < 9; ++tap) ws += wp[tap];
      s += ws * mi;
    }
    bias1[oc] = b1[oc] - s;
  }
}

// ---------------------------------------------------------------------------
// K4: generic 3x3 MFMA conv, NHWC bf16 in -> NHWC bf16 out (MODE 0) or
// fp32 NCHW out * xorig (MODE 1). Tile 16x16 px, 4 waves, 2 oc-groups.
// B staged in LDS [px18x18][ic32] bf16, 16B-unit XOR swizzle (q ^ (px&3)).
// A[icc][tap][oc][ic] bf16 from global, 72 VGPRs per icc.
// mfma_f32_16x16x32_bf16: A row=lane&15 (oc), B col=lane&15 (px),
// k=8*(lane>>4)+j (ic); D col=lane&15 (px), row=4*(lane>>4)+i (oc).
// ---------------------------------------------------------------------------
template <int CIN, int MODE>
__global__ void __launch_bounds__(256) k_conv_mfma(const u16* __restrict__ in,
                                                   const u16* __restrict__ Aw,
                                                   const float* __restrict__ bias,
                                                   u16* __restrict__ outb,
                                                   float* __restrict__ outf,
                                                   const float* __restrict__ xorig,
                                                   int H, int W) {
  constexpr int ICC = CIN / 32;
  __shared__ __align__(16) u16 bs[18 * 18 * 32];
  int t = threadIdx.x;
  int l = t & 63, wv = t >> 6;
  int ln = l & 15, q = l >> 4;
  int bz = blockIdx.z;
  int h0 = blockIdx.y * 16, w0 = blockIdx.x * 16;

  float4v acc[4][2];
#pragma unroll
  for (int i = 0; i < 4; ++i) {
    acc[i][0] = (float4v){0.f, 0.f, 0.f, 0.f};
    acc[i][1] = (float4v){0.f, 0.f, 0.f, 0.f};
  }

  for (int icc = 0; icc < ICC; ++icc) {
    // stage 18x18x32 bf16 (zero-pad), swizzled 16B units
    for (int u = t; u < 1296; u += 256) {
      int px = u >> 2, sq = u & 3;
      int ry = px / 18, rx = px - ry * 18;
      int gh = h0 - 1 + ry, gw = w0 - 1 + rx;
      uint4 v = {0, 0, 0, 0};
      if (gh >= 0 && gh < H && gw >= 0 && gw < W)
        v = *(const uint4*)&in[(((size_t)bz * H + gh) * W + gw) * CIN + icc * 32 + sq * 8];
      *(uint4*)((char*)bs + px * 64 + ((sq ^ (px & 3)) << 4)) = v;
    }
    // A fragments (global, L2-hot)
    short8v af[9][2];
#pragma unroll
    for (int tp = 0; tp < 9; ++tp) {
      af[tp][0] = *(const short8v*)&Aw[((size_t)(icc * 9 + tp) * 32 + ln) * 32 + q * 8];
      af[tp][1] = *(const short8v*)&Aw[((size_t)(icc * 9 + tp) * 32 + 16 + ln) * 32 + q * 8];
    }
    __syncthreads();
#pragma unroll
    for (int r4 = 0; r4 < 4; ++r4) {
      int r = wv * 4 + r4;
#pragma unroll
      for (int dy = 0; dy < 3; ++dy) {
#pragma unroll
        for (int dx = 0; dx < 3; ++dx) {
          int px = (r + dy) * 18 + ln + dx;
          short8v bf = *(const short8v*)((const char*)bs + px * 64 + ((q ^ (px & 3)) << 4));
          acc[r4][0] = __builtin_amdgcn_mfma_f32_16x16x32_bf16(af[dy * 3 + dx][0], bf, acc[r4][0], 0, 0, 0);
          acc[r4][1] = __builtin_amdgcn_mfma_f32_16x16x32_bf16(af[dy * 3 + dx][1], bf, acc[r4][1], 0, 0, 0);
        }
      }
    }
    if (ICC > 1) __syncthreads();
  }

#pragma unroll
  for (int r4 = 0; r4 < 4; ++r4) {
    int h = h0 + wv * 4 + r4;
    int wpix = w0 + ln;
#pragma unroll
    for (int g = 0; g < 2; ++g) {
      float v0 = acc[r4][g][0] + bias[g * 16 + q * 4 + 0];
      float v1 = acc[r4][g][1] + bias[g * 16 + q * 4 + 1];
      float v2 = acc[r4][g][2] + bias[g * 16 + q * 4 + 2];
      float v3 = acc[r4][g][3] + bias[g * 16 + q * 4 + 3];
      if (MODE == 0) {
        uint2 pk;
        pk.x = (uint)f2b(v0) | ((uint)f2b(v1) << 16);
        pk.y = (uint)f2b(v2) | ((uint)f2b(v3) << 16);
        *(uint2*)&outb[(((size_t)bz * H + h) * W + wpix) * 32 + g * 16 + q * 4] = pk;
      } else {
        float vv[4] = {v0, v1, v2, v3};
#pragma unroll
        for (int i = 0; i < 4; ++i) {
          int oc = g * 16 + q * 4 + i;
          size_t idx = (((size_t)bz * 32 + oc) * H + h) * W + wpix;
          outf[idx] = vv[i] * xorig[idx];
        }
      }
    }
  }
}

// ---------------------------------------------------------------------------
// K5: maxpool 2x2 NHWC bf16; thread = (b, ho, wo, c8-chunk).
// ---------------------------------------------------------------------------
__global__ void __launch_bounds__(256) k_pool(const u16* __restrict__ in,
                                              u16* __restrict__ out,
                                              int Ho, int Wo, int total) {
  int idx = blockIdx.x * 256 + threadIdx.x;
  if (idx >= total) return;
  int c8 = idx & 3;
  int rest = idx >> 2;
  int w = rest % Wo; rest /= Wo;
  int h = rest % Ho;
  int bb = rest / Ho;
  int Wi = Wo * 2;
  const u16* p0 = &in[(((size_t)bb * (Ho * 2) + 2 * h) * Wi + 2 * w) * 32 + c8 * 8];
  uint4 va = *(const uint4*)p0;
  uint4 vb = *(const uint4*)(p0 + 32);
  uint4 vc = *(const uint4*)(p0 + (size_t)Wi * 32);
  uint4 vd = *(const uint4*)(p0 + (size_t)Wi * 32 + 32);
  const u16* pa = (const u16*)&va;
  const u16* pb = (const u16*)&vb;
  const u16* pc = (const u16*)&vc;
  const u16* pd = (const u16*)&vd;
  u16 r[8];
#pragma unroll
  for (int j = 0; j < 8; ++j) {
    float m = fmaxf(fmaxf(b2f(pa[j]), b2f(pb[j])), fmaxf(b2f(pc[j]), b2f(pd[j])));
    r[j] = f2b(m);
  }
  *(uint4*)&out[(((size_t)bb * Ho + h) * Wo + w) * 32 + c8 * 8] = *(uint4*)r;
}

// ---------------------------------------------------------------------------
// K6: deconv 2x2 s2 as 4 parity 1x1 GEMMs via MFMA. Block = 16x16 INPUT px,
// z = b*4 + parity. B read direct from global NHWC.
// ---------------------------------------------------------------------------
__global__ void __launch_bounds__(256) k_deconv_mfma(const u16* __restrict__ in,
                                                     const u16* __restrict__ Aw,
                                                     const float* __restrict__ bias,
                                                     u16* __restrict__ out,
                                                     int Hi, int Wi) {
  int t = threadIdx.x;
  int l = t & 63, wv = t >> 6, ln = l & 15, q = l >> 4;
  int z = blockIdx.z, b = z >> 2, par = z & 3, p = par >> 1, qpar = par & 1;
  int h0 = blockIdx.y * 16, w0 = blockIdx.x * 16;
  int Ho = Hi * 2, Wo = Wi * 2;
  short8v af0 = *(const short8v*)&Aw[((size_t)par * 32 + ln) * 32 + q * 8];
  short8v af1 = *(const short8v*)&Aw[((size_t)par * 32 + 16 + ln) * 32 + q * 8];
#pragma unroll
  for (int r4 = 0; r4 < 4; ++r4) {
    int h = h0 + wv * 4 + r4;
    short8v bf = *(const short8v*)&in[(((size_t)b * Hi + h) * Wi + w0 + ln) * 32 + q * 8];
    float4v a0 = (float4v){0.f, 0.f, 0.f, 0.f};
    float4v a1 = (float4v){0.f, 0.f, 0.f, 0.f};
    a0 = __builtin_amdgcn_mfma_f32_16x16x32_bf16(af0, bf, a0, 0, 0, 0);
    a1 = __builtin_amdgcn_mfma_f32_16x16x32_bf16(af1, bf, a1, 0, 0, 0);
    int oh = 2 * h + p, ow = 2 * (w0 + ln) + qpar;
    size_t ob = (((size_t)b * Ho + oh) * Wo + ow) * 32;
    uint2 pk;
    pk.x = (uint)f2b(a0[0] + bias[q * 4 + 0]) | ((uint)f2b(a0[1] + bias[q * 4 + 1]) << 16);
    pk.y = (uint)f2b(a0[2] + bias[q * 4 + 2]) | ((uint)f2b(a0[3] + bias[q * 4 + 3]) << 16);
    *(uint2*)&out[ob + q * 4] = pk;
    pk.x = (uint)f2b(a1[0] + bias[16 + q * 4 + 0]) | ((uint)f2b(a1[1] + bias[16 + q * 4 + 1]) << 16);
    pk.y = (uint)f2b(a1[2] + bias[16 + q * 4 + 2]) | ((uint)f2b(a1[3] + bias[16 + q * 4 + 3]) << 16);
    *(uint2*)&out[ob + 16 + q * 4] = pk;
  }
}

// ---------------------------------------------------------------------------
extern "C" void kernel_launch(void* const* d_in, const int* in_sizes, int n_in,
                              void* d_out, int out_size, void* d_ws, size_t ws_size,
                              hipStream_t stream) {
  const float* x   = (const float*)d_in[0];
  const float* w1  = (const float*)d_in[1];
  const float* b1  = (const float*)d_in[2];
  const float* w2  = (const float*)d_in[3];
  const float* b2  = (const float*)d_in[4];
  const float* w3  = (const float*)d_in[5];
  const float* b3  = (const float*)d_in[6];
  const float* w4  = (const float*)d_in[7];
  const float* b4  = (const float*)d_in[8];
  const float* w5  = (const float*)d_in[9];
  const float* b5  = (const float*)d_in[10];
  const float* w6  = (const float*)d_in[11];
  const float* b6  = (const float*)d_in[12];
  const float* w7  = (const float*)d_in[13];
  const float* b7  = (const float*)d_in[14];
  const float* dw1 = (const float*)d_in[15];
  const float* db1 = (const float*)d_in[16];
  const float* dw2 = (const float*)d_in[17];
  const float* db2 = (const float*)d_in[18];
  const float* dw3 = (const float*)d_in[19];
  const float* db3 = (const float*)d_in[20];
  float* out = (float*)d_out;
  char* wsb = (char*)d_ws;

  // ws layout (bytes); opm region later reused by p1..t6 (stream-ordered safe)
  u16* opm = (u16*)(wsb + 0);                 // 83,886,080 per-b branch maps
  u16* p1  = (u16*)(wsb + 0);
  u16* t2  = (u16*)(wsb + 16777216ull);
  u16* p2  = (u16*)(wsb + 33554432ull);
  u16* t3  = (u16*)(wsb + 37748736ull);
  u16* p3  = (u16*)(wsb + 41943040ull);
  u16* t4  = (u16*)(wsb + 42991616ull);
  u16* dc1 = (u16*)(wsb + 44040192ull);
  u16* t5  = (u16*)(wsb + 48234496ull);
  u16* dc2 = (u16*)(wsb + 52428800ull);
  u16* t6  = (u16*)(wsb + 69206016ull);
  u16* t1  = (u16*)(wsb + 85983232ull);       // 67,108,864
  u16* dc3 = (u16*)(wsb + 153092096ull);      // 67,108,864
  u16* A1  = (u16*)(wsb + 220200960ull);      // 92,160
  u16* A2  = (u16*)(wsb + 220293120ull);
  u16* A3  = (u16*)(wsb + 220311552ull);
  u16* A4  = (u16*)(wsb + 220329984ull);
  u16* A5  = (u16*)(wsb + 220348416ull);
  u16* A6  = (u16*)(wsb + 220366848ull);
  u16* A7  = (u16*)(wsb + 220385280ull);
  u16* Ad1 = (u16*)(wsb + 220403712ull);
  u16* Ad2 = (u16*)(wsb + 220411904ull);
  u16* Ad3 = (u16*)(wsb + 220420096ull);
  float* bias1 = (float*)(wsb + 220428288ull);
  float* partS = (float*)(wsb + 220428416ull);
  float* partQ = (float*)(wsb + 220756096ull);
  float* stats = (float*)(wsb + 221083776ull);

  k_prep_shared<<<264, 256, 0, stream>>>(w2, w3, w4, w5, w6, w7, dw1, dw2, dw3,
                                         A2, A3, A4, A5, A6, A7, Ad1, Ad2, Ad3);

  for (int b = 0; b < 4; ++b) {
    k_opfused<<<dim3(8, 512), 256, 0, stream>>>(x, b, opm, partS, partQ);
    k_stats5<<<5, 256, 0, stream>>>(partS, partQ, stats);
    k_prep_b<<<181, 256, 0, stream>>>(w1, b1, stats, A1, bias1);
    k_conv_mfma<160, 0><<<dim3(32, 32, 1), 256, 0, stream>>>(
        opm, A1, bias1, t1 + (size_t)b * 512 * 512 * 32, nullptr, nullptr, 512, 512);
  }

  k_pool<<<4096, 256, 0, stream>>>(t1, p1, 256, 256, 4 * 256 * 256 * 4);
  k_conv_mfma<32, 0><<<dim3(16, 16, 4), 256, 0, stream>>>(p1, A2, b2, t2, nullptr, nullptr, 256, 256);
  k_pool<<<1024, 256, 0, stream>>>(t2, p2, 128, 128, 4 * 128 * 128 * 4);
  k_conv_mfma<32, 0><<<dim3(8, 8, 4), 256, 0, stream>>>(p2, A3, b3, t3, nullptr, nullptr, 128, 128);
  k_pool<<<256, 256, 0, stream>>>(t3, p3, 64, 64, 4 * 64 * 64 * 4);
  k_conv_mfma<32, 0><<<dim3(4, 4, 4), 256, 0, stream>>>(p3, A4, b4, t4, nullptr, nullptr, 64, 64);
  k_deconv_mfma<<<dim3(4, 4, 16), 256, 0, stream>>>(t4, Ad1, db1, dc1, 64, 64);
  k_conv_mfma<32, 0><<<dim3(8, 8, 4), 256, 0, stream>>>(dc1, A5, b5, t5, nullptr, nullptr, 128, 128);
  k_deconv_mfma<<<dim3(8, 8, 16), 256, 0, stream>>>(t5, Ad2, db2, dc2, 128, 128);
  k_conv_mfma<32, 0><<<dim3(16, 16, 4), 256, 0, stream>>>(dc2, A6, b6, t6, nullptr, nullptr, 256, 256);
  k_deconv_mfma<<<dim3(16, 16, 16), 256, 0, stream>>>(t6, Ad3, db3, dc3, 256, 256);
  k_conv_mfma<32, 1><<<dim3(32, 32, 4), 256, 0, stream>>>(dc3, A7, b7, nullptr, out, x, 512, 512);
}

// Round 5
// 791.004 us; speedup vs baseline: 5.2052x; 1.2223x over previous
//
#include <hip/hip_runtime.h>
#include <hip/hip_bf16.h>
#include <cstddef>

// B=4, C=32, H=W=512. NHWC bf16 MFMA pipeline.
//  k_prep_shared: conv2..7 + deconv weights -> bf16 MFMA A-layout
//  k_opstats/k_stats: per-(b,branch) mean/istd from x (validated round 3)
//  k_prep_b_all: fold norm into conv1 weights/bias for all 4 samples
//  per b: k_opfused (stencils -> bf16 NHWC raw maps), k_conv_mfma<160,2> conv1+pool
//  conv2+pool, conv3+pool, conv4, [deconv conv] x3; conv7 fuses *x, fp32 NCHW out.

typedef unsigned short u16;
typedef unsigned int uint;
typedef __attribute__((ext_vector_type(8))) short short8v;
typedef __attribute__((ext_vector_type(4))) float float4v;

constexpr int Bn = 4, Cn = 32, Hn = 512, Wn = 512;
constexpr int PLANE = Hn * Wn;

__device__ __forceinline__ u16 f2b(float f) {
  union { float f; uint i; } c; c.f = f;
  uint r = c.i + 0x7FFFu + ((c.i >> 16) & 1u);
  return (u16)(r >> 16);
}

static __device__ __forceinline__ int reflect_idx(int i, int n) {
  return i < 0 ? -i : (i >= n ? 2 * n - 2 - i : i);
}

// Combined stencils (0.5*(Kx+Ky) folded); validated rounds 3-4.
#define BRANCH_VALS(n00, n01, n02, n10, n11, n12, n20, n21, n22, v1, v2, v3, v4, v5)        \
  do {                                                                                      \
    v1 = -(n00 + n01 + n10) + (n12 + n21 + n22);                                            \
    v2 = -3.f * n00 - 5.f * n01 - 5.f * n10 + 5.f * n12 + 5.f * n21 + 3.f * n22;            \
    v3 = 2.f * (n00 + n02 + n20 + n22) - 8.f * n11;                                         \
    v4 = 0.5f * (-n00 - n01 + n10 + n11);                                                   \
    v5 = 0.5f * n01 + n02 - 0.5f * n10 + 0.5f * n12 - n20 - 0.5f * n21;                     \
  } while (0)

// ---------------------------------------------------------------------------
// Stats pass over x (all samples): per-(b,br) partial (sum, sumsq).
// Validated in round 3.
// ---------------------------------------------------------------------------
__global__ void __launch_bounds__(128) k_opstats(const float* __restrict__ x,
                                                 float* __restrict__ partS,
                                                 float* __restrict__ partQ) {
  int bid = blockIdx.x;  // 8192
  int b = bid >> 11;
  int local = bid & 2047;
  int c = local >> 6;
  int chunk = local & 63;
  int t = threadIdx.x;
  int w0 = t * 4;
  const float* xp = x + (size_t)(b * Cn + c) * PLANE;
  int h0 = chunk * 8;

  int ci[6];
#pragma unroll
  for (int j = 0; j < 6; j++) ci[j] = reflect_idx(w0 - 1 + j, Wn);

  float ap[6], ac[6], an[6];
  {
    const float* rp = xp + reflect_idx(h0 - 1, Hn) * Wn;
#pragma unroll
    for (int j = 0; j < 6; j++) ap[j] = rp[ci[j]];
  }
  {
    const float* rp = xp + h0 * Wn;
#pragma unroll
    for (int j = 0; j < 6; j++) ac[j] = rp[ci[j]];
  }

  float s[5] = {0, 0, 0, 0, 0}, q[5] = {0, 0, 0, 0, 0};
#pragma unroll
  for (int r = 0; r < 8; ++r) {
    int h = h0 + r;
    const float* rp = xp + reflect_idx(h + 1, Hn) * Wn;
#pragma unroll
    for (int j = 0; j < 6; j++) an[j] = rp[ci[j]];
#pragma unroll
    for (int k = 0; k < 4; ++k) {
      float v1, v2, v3, v4, v5;
      BRANCH_VALS(ap[k], ap[k + 1], ap[k + 2], ac[k], ac[k + 1], ac[k + 2],
                  an[k], an[k + 1], an[k + 2], v1, v2, v3, v4, v5);
      s[0] += v1; q[0] += v1 * v1;
      s[1] += v2; q[1] += v2 * v2;
      s[2] += v3; q[2] += v3 * v3;
      s[3] += v4; q[3] += v4 * v4;
      s[4] += v5; q[5 - 1] += v5 * v5;
    }
#pragma unroll
    for (int j = 0; j < 6; j++) { ap[j] = ac[j]; ac[j] = an[j]; }
  }

#pragma unroll
  for (int i = 0; i < 5; i++) {
    float ss = s[i], qq = q[i];
#pragma unroll
    for (int off = 32; off > 0; off >>= 1) {
      ss += __shfl_down(ss, off);
      qq += __shfl_down(qq, off);
    }
    if ((t & 63) == 0) {
      int wv = t >> 6;
      int g = b * 5 + i;
      int idx = (c * 64 + chunk) * 2 + wv;
      partS[(size_t)g * 4096 + idx] = ss;
      partQ[(size_t)g * 4096 + idx] = qq;
    }
  }
}

__global__ void __launch_bounds__(256) k_stats(const float* __restrict__ partS,
                                               const float* __restrict__ partQ,
                                               float* __restrict__ stats) {
  __shared__ float red[256];
  int g = blockIdx.x;  // 20
  int t = threadIdx.x;
  float ss = 0.f, qq = 0.f;
  const float* ps = partS + (size_t)g * 4096;
  const float* pq = partQ + (size_t)g * 4096;
  for (int i = t; i < 4096; i += 256) {
    ss += ps[i];
    qq += pq[i];
  }
  red[t] = ss;
  __syncthreads();
  for (int o = 128; o > 0; o >>= 1) {
    if (t < o) red[t] += red[t + o];
    __syncthreads();
  }
  float S = red[0];
  __syncthreads();
  red[t] = qq;
  __syncthreads();
  for (int o = 128; o > 0; o >>= 1) {
    if (t < o) red[t] += red[t + o];
    __syncthreads();
  }
  if (t == 0) {
    const float N = 8388608.0f;
    float mean = S / N;
    float var = red[0] / N - mean * mean;
    stats[g * 2] = mean;
    stats[g * 2 + 1] = 1.0f / sqrtf(var);
  }
}

// ---------------------------------------------------------------------------
// Operator pass for one sample: raw bf16 branch maps NHWC via LDS transpose.
// Grid (8 wchunks, 512 h), 256 thr: px = t&63, cg = t>>6 (4 ch/thread x 8 it).
// ---------------------------------------------------------------------------
__global__ void __launch_bounds__(256) k_opfused(const float* __restrict__ x, int b,
                                                 u16* __restrict__ opm) {
  __shared__ u16 lin[160 * 66];
  int t = threadIdx.x;
  int px = t & 63, cg = t >> 6;
  int h = blockIdx.y;
  int w = blockIdx.x * 64 + px;
  int hm = h == 0 ? 1 : h - 1, hp = h == 511 ? 510 : h + 1;
  int wm = w == 0 ? 1 : w - 1, wp = w == 511 ? 510 : w + 1;

#pragma unroll
  for (int it = 0; it < 8; ++it) {
    int c = it * 4 + cg;
    const float* xp = x + ((size_t)(b * 32 + c) * 512) * 512;
    const float* r0 = xp + (size_t)hm * 512;
    const float* r1 = xp + (size_t)h * 512;
    const float* r2 = xp + (size_t)hp * 512;
    float n00 = r0[wm], n01 = r0[w], n02 = r0[wp];
    float n10 = r1[wm], n11 = r1[w], n12 = r1[wp];
    float n20 = r2[wm], n21 = r2[w], n22 = r2[wp];
    float v1, v2, v3, v4, v5;
    BRANCH_VALS(n00, n01, n02, n10, n11, n12, n20, n21, n22, v1, v2, v3, v4, v5);
    lin[(c) * 66 + px] = f2b(v1);
    lin[(32 + c) * 66 + px] = f2b(v2);
    lin[(64 + c) * 66 + px] = f2b(v3);
    lin[(96 + c) * 66 + px] = f2b(v4);
    lin[(128 + c) * 66 + px] = f2b(v5);
  }
  __syncthreads();

  size_t obase = ((size_t)h * 512 + blockIdx.x * 64) * 160;
#pragma unroll
  for (int i = 0; i < 5; ++i) {
    int u = t + i * 256;           // 1280 units = 64 px x 20 ch-octets
    int pxi = u / 20, chg = u % 20;
    u16 tmp[8];
#pragma unroll
    for (int j = 0; j < 8; ++j) tmp[j] = lin[(chg * 8 + j) * 66 + pxi];
    *(uint4*)&opm[obase + (size_t)pxi * 160 + chg * 8] = *(uint4*)tmp;
  }
}

// ---------------------------------------------------------------------------
// Shared weight prep: conv2..7 -> A[tap][oc][ic]; deconv -> Adc[par][oc][ic].
// ---------------------------------------------------------------------------
__global__ void __launch_bounds__(256) k_prep_shared(
    const float* w2, const float* w3, const float* w4, const float* w5,
    const float* w6, const float* w7, const float* dw1, const float* dw2,
    const float* dw3, u16* A2, u16* A3, u16* A4, u16* A5, u16* A6, u16* A7,
    u16* Ad1, u16* Ad2, u16* Ad3) {
  int id = blockIdx.x * 256 + threadIdx.x;
  if (id < 55296) {
    int s = id / 9216, r = id % 9216;
    int tap = r / 1024, oc = (r >> 5) & 31, ic = r & 31;
    const float* w = s == 0 ? w2 : s == 1 ? w3 : s == 2 ? w4 : s == 3 ? w5 : s == 4 ? w6 : w7;
    u16* A = s == 0 ? A2 : s == 1 ? A3 : s == 2 ? A4 : s == 3 ? A5 : s == 4 ? A6 : A7;
    A[r] = f2b(w[(oc * 32 + ic) * 9 + tap]);
  } else if (id < 67584) {
    int r = id - 55296;
    int s = r / 4096, e = r % 4096;
    int par = e >> 10, oc = (e >> 5) & 31, ic = e & 31;
    const float* w = s == 0 ? dw1 : s == 1 ? dw2 : dw3;
    u16* A = s == 0 ? Ad1 : s == 1 ? Ad2 : Ad3;
    A[e] = f2b(w[(ic * 32 + oc) * 4 + par]);
  }
}

// ---------------------------------------------------------------------------
// conv1 prep for ALL samples: A1all[b][br][tap][oc][ic] = bf16(w1 * istd);
// bias1all[b][oc] = b1[oc] - sum w1*mean*istd.
// ---------------------------------------------------------------------------
__global__ void __launch_bounds__(256) k_prep_b_all(const float* __restrict__ w1,
                                                    const float* __restrict__ b1,
                                                    const float* __restrict__ stats,
                                                    u16* __restrict__ A1all,
                                                    float* __restrict__ bias1all) {
  int e = blockIdx.x * 256 + threadIdx.x;
  if (e < 184320) {
    int b = e / 46080, r = e % 46080;
    int br = r / 9216, r2 = r % 9216;
    int tap = r2 / 1024, oc = (r2 >> 5) & 31, ic = r2 & 31;
    A1all[e] = f2b(w1[(oc * 160 + br * 32 + ic) * 9 + tap] * stats[(b * 5 + br) * 2 + 1]);
  } else if (e < 184448) {
    int t2 = e - 184320;
    int b = t2 >> 5, oc = t2 & 31;
    float s = 0.f;
    for (int ch = 0; ch < 160; ++ch) {
      int br = ch >> 5;
      float mi = stats[(b * 5 + br) * 2] * stats[(b * 5 + br) * 2 + 1];
      const float* wp = w1 + (size_t)(oc * 160 + ch) * 9;
      float ws = 0.f;
#pragma unroll
      for (int tap = 0; tap < 9; ++tap) ws += wp[tap];
      s += ws * mi;
    }
    bias1all[b * 32 + oc] = b1[oc] - s;
  }
}

// ---------------------------------------------------------------------------
// Generic 3x3 MFMA conv, NHWC bf16 in. MODE 0: bf16 NHWC out.
// MODE 1: fp32 NCHW out * xorig (LDS-transposed float4 epilogue).
// MODE 2: fused maxpool2x2 -> bf16 NHWC out at (H/2, W/2).
// Tile 16x16 px, 4 waves, 2 oc-groups; B in LDS [px18x18][ic32] 16B-swizzled.
// ---------------------------------------------------------------------------
template <int CIN, int MODE>
__global__ void __launch_bounds__(256) k_conv_mfma(const u16* __restrict__ in,
                                                   const u16* __restrict__ Aw,
                                                   const float* __restrict__ bias,
                                                   u16* __restrict__ outb,
                                                   float* __restrict__ outf,
                                                   const float* __restrict__ xorig,
                                                   int H, int W) {
  constexpr int ICC = CIN / 32;
  __shared__ __align__(16) char smem[(MODE == 1) ? 32768 : 20736];
  u16* bs = (u16*)smem;
  int t = threadIdx.x;
  int l = t & 63, wv = t >> 6;
  int ln = l & 15, q = l >> 4;
  int bz = blockIdx.z;
  int h0 = blockIdx.y * 16, w0 = blockIdx.x * 16;

  float4v acc[4][2];
#pragma unroll
  for (int i = 0; i < 4; ++i) {
    acc[i][0] = (float4v){0.f, 0.f, 0.f, 0.f};
    acc[i][1] = (float4v){0.f, 0.f, 0.f, 0.f};
  }

  for (int icc = 0; icc < ICC; ++icc) {
    for (int u = t; u < 1296; u += 256) {
      int px = u >> 2, sq = u & 3;
      int ry = px / 18, rx = px - ry * 18;
      int gh = h0 - 1 + ry, gw = w0 - 1 + rx;
      uint4 v = {0, 0, 0, 0};
      if (gh >= 0 && gh < H && gw >= 0 && gw < W)
        v = *(const uint4*)&in[(((size_t)bz * H + gh) * W + gw) * CIN + icc * 32 + sq * 8];
      *(uint4*)((char*)bs + px * 64 + ((sq ^ (px & 3)) << 4)) = v;
    }
    short8v af[9][2];
#pragma unroll
    for (int tp = 0; tp < 9; ++tp) {
      af[tp][0] = *(const short8v*)&Aw[((size_t)(icc * 9 + tp) * 32 + ln) * 32 + q * 8];
      af[tp][1] = *(const short8v*)&Aw[((size_t)(icc * 9 + tp) * 32 + 16 + ln) * 32 + q * 8];
    }
    __syncthreads();
#pragma unroll
    for (int r4 = 0; r4 < 4; ++r4) {
      int r = wv * 4 + r4;
#pragma unroll
      for (int dy = 0; dy < 3; ++dy) {
#pragma unroll
        for (int dx = 0; dx < 3; ++dx) {
          int px = (r + dy) * 18 + ln + dx;
          short8v bf = *(const short8v*)((const char*)bs + px * 64 + ((q ^ (px & 3)) << 4));
          acc[r4][0] = __builtin_amdgcn_mfma_f32_16x16x32_bf16(af[dy * 3 + dx][0], bf, acc[r4][0], 0, 0, 0);
          acc[r4][1] = __builtin_amdgcn_mfma_f32_16x16x32_bf16(af[dy * 3 + dx][1], bf, acc[r4][1], 0, 0, 0);
        }
      }
    }
    if (ICC > 1) __syncthreads();
  }

  if (MODE == 0) {
#pragma unroll
    for (int r4 = 0; r4 < 4; ++r4) {
      int h = h0 + wv * 4 + r4;
      int wpix = w0 + ln;
#pragma unroll
      for (int g = 0; g < 2; ++g) {
        float v0 = acc[r4][g][0] + bias[g * 16 + q * 4 + 0];
        float v1 = acc[r4][g][1] + bias[g * 16 + q * 4 + 1];
        float v2 = acc[r4][g][2] + bias[g * 16 + q * 4 + 2];
        float v3 = acc[r4][g][3] + bias[g * 16 + q * 4 + 3];
        uint2 pk;
        pk.x = (uint)f2b(v0) | ((uint)f2b(v1) << 16);
        pk.y = (uint)f2b(v2) | ((uint)f2b(v3) << 16);
        *(uint2*)&outb[(((size_t)bz * H + h) * W + wpix) * 32 + g * 16 + q * 4] = pk;
      }
    }
  } else if (MODE == 2) {
    // fused maxpool 2x2: r4-pairs within lane, w-pairs via shfl_xor(1)
    int Hp = H >> 1, Wp = W >> 1;
#pragma unroll
    for (int rp = 0; rp < 2; ++rp) {
#pragma unroll
      for (int g = 0; g < 2; ++g) {
        float m0 = fmaxf(acc[2 * rp][g][0], acc[2 * rp + 1][g][0]);
        float m1 = fmaxf(acc[2 * rp][g][1], acc[2 * rp + 1][g][1]);
        float m2 = fmaxf(acc[2 * rp][g][2], acc[2 * rp + 1][g][2]);
        float m3 = fmaxf(acc[2 * rp][g][3], acc[2 * rp + 1][g][3]);
        m0 = fmaxf(m0, __shfl_xor(m0, 1));
        m1 = fmaxf(m1, __shfl_xor(m1, 1));
        m2 = fmaxf(m2, __shfl_xor(m2, 1));
        m3 = fmaxf(m3, __shfl_xor(m3, 1));
        if (!(l & 1)) {
          int ph = (h0 >> 1) + wv * 2 + rp;
          int pw = (w0 >> 1) + (ln >> 1);
          uint2 pk;
          pk.x = (uint)f2b(m0 + bias[g * 16 + q * 4 + 0]) |
                 ((uint)f2b(m1 + bias[g * 16 + q * 4 + 1]) << 16);
          pk.y = (uint)f2b(m2 + bias[g * 16 + q * 4 + 2]) |
                 ((uint)f2b(m3 + bias[g * 16 + q * 4 + 3]) << 16);
          *(uint2*)&outb[(((size_t)bz * Hp + ph) * Wp + pw) * 32 + g * 16 + q * 4] = pk;
        }
      }
    }
  } else {
    // MODE 1: LDS transpose -> float4 along w, fused *xorig, fp32 NCHW
    float* os = (float*)smem;
    __syncthreads();  // bs no longer needed by any wave
#pragma unroll
    for (int r4 = 0; r4 < 4; ++r4) {
      int hl = wv * 4 + r4;
#pragma unroll
      for (int g = 0; g < 2; ++g) {
#pragma unroll
        for (int i = 0; i < 4; ++i) {
          int oc = g * 16 + q * 4 + i;
          os[(oc * 16 + hl) * 16 + ln] = acc[r4][g][i] + bias[oc];
        }
      }
    }
    __syncthreads();
#pragma unroll
    for (int j = 0; j < 8; ++j) {
      int u = t + j * 256;  // 2048 float4 units: [oc][h][wq]
      int wq = u & 3, hh = (u >> 2) & 15, oc = u >> 6;
      float4v v = *(const float4v*)&os[(oc * 16 + hh) * 16 + wq * 4];
      size_t gidx = (((size_t)bz * 32 + oc) * H + h0 + hh) * W + w0 + wq * 4;
      float4v xo = *(const float4v*)&xorig[gidx];
      v[0] *= xo[0]; v[1] *= xo[1]; v[2] *= xo[2]; v[3] *= xo[3];
      *(float4v*)&outf[gidx] = v;
    }
  }
}

// ---------------------------------------------------------------------------
// deconv 2x2 s2 as 4 parity 1x1 GEMMs via MFMA.
// ---------------------------------------------------------------------------
__global__ void __launch_bounds__(256) k_deconv_mfma(const u16* __restrict__ in,
                                                     const u16* __restrict__ Aw,
                                                     const float* __restrict__ bias,
                                                     u16* __restrict__ out,
                                                     int Hi, int Wi) {
  int t = threadIdx.x;
  int l = t & 63, wv = t >> 6, ln = l & 15, q = l >> 4;
  int z = blockIdx.z, b = z >> 2, par = z & 3, p = par >> 1, qpar = par & 1;
  int h0 = blockIdx.y * 16, w0 = blockIdx.x * 16;
  int Ho = Hi * 2, Wo = Wi * 2;
  short8v af0 = *(const short8v*)&Aw[((size_t)par * 32 + ln) * 32 + q * 8];
  short8v af1 = *(const short8v*)&Aw[((size_t)par * 32 + 16 + ln) * 32 + q * 8];
#pragma unroll
  for (int r4 = 0; r4 < 4; ++r4) {
    int h = h0 + wv * 4 + r4;
    short8v bf = *(const short8v*)&in[(((size_t)b * Hi + h) * Wi + w0 + ln) * 32 + q * 8];
    float4v a0 = (float4v){0.f, 0.f, 0.f, 0.f};
    float4v a1 = (float4v){0.f, 0.f, 0.f, 0.f};
    a0 = __builtin_amdgcn_mfma_f32_16x16x32_bf16(af0, bf, a0, 0, 0, 0);
    a1 = __builtin_amdgcn_mfma_f32_16x16x32_bf16(af1, bf, a1, 0, 0, 0);
    int oh = 2 * h + p, ow = 2 * (w0 + ln) + qpar;
    size_t ob = (((size_t)b * Ho + oh) * Wo + ow) * 32;
    uint2 pk;
    pk.x = (uint)f2b(a0[0] + bias[q * 4 + 0]) | ((uint)f2b(a0[1] + bias[q * 4 + 1]) << 16);
    pk.y = (uint)f2b(a0[2] + bias[q * 4 + 2]) | ((uint)f2b(a0[3] + bias[q * 4 + 3]) << 16);
    *(uint2*)&out[ob + q * 4] = pk;
    pk.x = (uint)f2b(a1[0] + bias[16 + q * 4 + 0]) | ((uint)f2b(a1[1] + bias[16 + q * 4 + 1]) << 16);
    pk.y = (uint)f2b(a1[2] + bias[16 + q * 4 + 2]) | ((uint)f2b(a1[3] + bias[16 + q * 4 + 3]) << 16);
    *(uint2*)&out[ob + 16 + q * 4] = pk;
  }
}

// ---------------------------------------------------------------------------
extern "C" void kernel_launch(void* const* d_in, const int* in_sizes, int n_in,
                              void* d_out, int out_size, void* d_ws, size_t ws_size,
                              hipStream_t stream) {
  const float* x   = (const float*)d_in[0];
  const float* w1  = (const float*)d_in[1];
  const float* b1  = (const float*)d_in[2];
  const float* w2  = (const float*)d_in[3];
  const float* b2  = (const float*)d_in[4];
  const float* w3  = (const float*)d_in[5];
  const float* b3  = (const float*)d_in[6];
  const float* w4  = (const float*)d_in[7];
  const float* b4  = (const float*)d_in[8];
  const float* w5  = (const float*)d_in[9];
  const float* b5  = (const float*)d_in[10];
  const float* w6  = (const float*)d_in[11];
  const float* b6  = (const float*)d_in[12];
  const float* w7  = (const float*)d_in[13];
  const float* b7  = (const float*)d_in[14];
  const float* dw1 = (const float*)d_in[15];
  const float* db1 = (const float*)d_in[16];
  const float* dw2 = (const float*)d_in[17];
  const float* db2 = (const float*)d_in[18];
  const float* dw3 = (const float*)d_in[19];
  const float* db3 = (const float*)d_in[20];
  float* out = (float*)d_out;
  char* wsb = (char*)d_ws;

  u16* opm   = (u16*)(wsb + 0);             // 83,886,080 (per-sample)
  u16* p1    = (u16*)(wsb + 83886080ull);   // 16,777,216
  u16* p2    = (u16*)(wsb + 100663296ull);  //  4,194,304
  u16* p3    = (u16*)(wsb + 104857600ull);  //  1,048,576
  u16* t4    = (u16*)(wsb + 105906176ull);  //  1,048,576
  u16* dc1   = (u16*)(wsb + 106954752ull);  //  4,194,304
  u16* t5    = (u16*)(wsb + 111149056ull);  //  4,194,304
  u16* dc2   = (u16*)(wsb + 115343360ull);  // 16,777,216
  u16* t6    = (u16*)(wsb + 132120576ull);  // 16,777,216
  u16* dc3   = (u16*)(wsb + 148897792ull);  // 67,108,864
  u16* A1all = (u16*)(wsb + 216006656ull);  //    368,640
  u16* A2    = (u16*)(wsb + 216375296ull);
  u16* A3    = (u16*)(wsb + 216393728ull);
  u16* A4    = (u16*)(wsb + 216412160ull);
  u16* A5    = (u16*)(wsb + 216430592ull);
  u16* A6    = (u16*)(wsb + 216449024ull);
  u16* A7    = (u16*)(wsb + 216467456ull);
  u16* Ad1   = (u16*)(wsb + 216485888ull);
  u16* Ad2   = (u16*)(wsb + 216494080ull);
  u16* Ad3   = (u16*)(wsb + 216502272ull);
  float* bias1all = (float*)(wsb + 216510464ull);
  float* partS    = (float*)(wsb + 216510976ull);
  float* partQ    = (float*)(wsb + 216838656ull);
  float* stats    = (float*)(wsb + 217166336ull);

  k_prep_shared<<<264, 256, 0, stream>>>(w2, w3, w4, w5, w6, w7, dw1, dw2, dw3,
                                         A2, A3, A4, A5, A6, A7, Ad1, Ad2, Ad3);
  k_opstats<<<8192, 128, 0, stream>>>(x, partS, partQ);
  k_stats<<<20, 256, 0, stream>>>(partS, partQ, stats);
  k_prep_b_all<<<721, 256, 0, stream>>>(w1, b1, stats, A1all, bias1all);

  for (int b = 0; b < 4; ++b) {
    k_opfused<<<dim3(8, 512), 256, 0, stream>>>(x, b, opm);
    k_conv_mfma<160, 2><<<dim3(32, 32, 1), 256, 0, stream>>>(
        opm, A1all + (size_t)b * 46080, bias1all + b * 32,
        p1 + (size_t)b * 256 * 256 * 32, nullptr, nullptr, 512, 512);
  }

  k_conv_mfma<32, 2><<<dim3(16, 16, 4), 256, 0, stream>>>(p1, A2, b2, p2, nullptr, nullptr, 256, 256);
  k_conv_mfma<32, 2><<<dim3(8, 8, 4), 256, 0, stream>>>(p2, A3, b3, p3, nullptr, nullptr, 128, 128);
  k_conv_mfma<32, 0><<<dim3(4, 4, 4), 256, 0, stream>>>(p3, A4, b4, t4, nullptr, nullptr, 64, 64);
  k_deconv_mfma<<<dim3(4, 4, 16), 256, 0, stream>>>(t4, Ad1, db1, dc1, 64, 64);
  k_conv_mfma<32, 0><<<dim3(8, 8, 4), 256, 0, stream>>>(dc1, A5, b5, t5, nullptr, nullptr, 128, 128);
  k_deconv_mfma<<<dim3(8, 8, 16), 256, 0, stream>>>(t5, Ad2, db2, dc2, 128, 128);
  k_conv_mfma<32, 0><<<dim3(16, 16, 4), 256, 0, stream>>>(dc2, A6, b6, t6, nullptr, nullptr, 256, 256);
  k_deconv_mfma<<<dim3(16, 16, 16), 256, 0, stream>>>(t6, Ad3, db3, dc3, 256, 256);
  k_conv_mfma<32, 1><<<dim3(32, 32, 4), 256, 0, stream>>>(dc3, A7, b7, nullptr, out, x, 512, 512);
}